// Round 1
// baseline (111.431 us; speedup 1.0000x reference)
//
#include <hip/hip_runtime.h>
#include <hip/hip_bf16.h>

#define NN 96
#define DD 64
#define HH 256
#define H2 128

// ---------------- Kernel A: projections ----------------
// pi = X@W1[:64] + b1, pj = X@W1[64:]
// ta = X@V1[:64] + c1, tb = X@V1[64:128], tcT[h][k] = (X@V1[128:])[k][h]
__global__ __launch_bounds__(256) void proj_kernel(
    const float* __restrict__ X, const float* __restrict__ W1, const float* __restrict__ b1,
    const float* __restrict__ V1, const float* __restrict__ c1,
    float* __restrict__ pi, float* __restrict__ pj,
    float* __restrict__ ta, float* __restrict__ tb, float* __restrict__ tcT)
{
    const int i = blockIdx.x;
    const int h = threadIdx.x;          // 0..255
    __shared__ float xs[DD];
    if (h < DD) xs[h] = X[i*DD + h];
    __syncthreads();
    float aPi = 0.f, aPj = 0.f, aTa = 0.f, aTb = 0.f, aTc = 0.f;
    #pragma unroll 8
    for (int d = 0; d < DD; ++d) {
        const float x = xs[d];
        aPi = fmaf(x, W1[d*HH + h],          aPi);
        aPj = fmaf(x, W1[(DD + d)*HH + h],   aPj);
        aTa = fmaf(x, V1[d*HH + h],          aTa);
        aTb = fmaf(x, V1[(DD + d)*HH + h],   aTb);
        aTc = fmaf(x, V1[(2*DD + d)*HH + h], aTc);
    }
    pi[i*HH + h] = aPi + b1[h];
    pj[i*HH + h] = aPj;
    ta[i*HH + h] = aTa + c1[h];
    tb[i*HH + h] = aTb;
    tcT[h*NN + i] = aTc;
}

// ---------------- Kernel B: causal [96,96] ----------------
// grid (96, 8): one i, 12 j per block in 2 batches of 6.
// 256 threads: c = t&127 (layer-2 output channel), half = t>>7 (h-slice).
// W2 column slice in 128 registers. h-tile staged transposed hbT[h][jj],
// XOR-swizzled columns -> conflict-free staging writes, broadcast b128 reads.
#define JBATCH 6
__global__ __launch_bounds__(256, 3) void causal_kernel(
    const float* __restrict__ pi, const float* __restrict__ pj,
    const float* __restrict__ W2, const float* __restrict__ b2,
    const float* __restrict__ W3, const float* __restrict__ b3,
    float* __restrict__ out)
{
    const int i  = blockIdx.x;
    const int j0 = blockIdx.y * (2*JBATCH);
    const int t  = threadIdx.x;         // 0..255
    const int c    = t & (H2 - 1);
    const int half = t >> 7;

    __shared__ float hbT[HH][8];        // [h][jj], swizzled; 8 KB (reused as partial)
    __shared__ float red[2][JBATCH];

    float w[128];
    #pragma unroll
    for (int q = 0; q < 128; ++q) w[q] = W2[(half*128 + q)*H2 + c];

    const float p_i = pi[i*HH + t];     // thread t <-> h = t
    const float b2c = b2[c];
    const float w3c = W3[c];
    const float b3v = b3[0];
    const int   sw  = (t >> 2) & 7;     // storage swizzle for row h = t

    for (int batch = 0; batch < 2; ++batch) {
        const int jb0 = j0 + batch*JBATCH;

        // ---- stage: hbT[h][jj^sw] = relu(pi + pj), conflict-free writes ----
        #pragma unroll
        for (int jj = 0; jj < JBATCH; ++jj)
            hbT[t][jj ^ sw] = fmaxf(p_i + pj[(jb0 + jj)*HH + t], 0.f);
        __syncthreads();

        // ---- inner: acc[jj] += hb[h][jj] * W2[h][c] over this half's h ----
        float acc[JBATCH];
        #pragma unroll
        for (int jj = 0; jj < JBATCH; ++jj) acc[jj] = 0.f;
        #pragma unroll
        for (int q = 0; q < 128; ++q) {
            const int s = (q >> 2) & 7;                  // compile-time
            const float4 r0 = *(const float4*)&hbT[half*128 + q][0];
            const float4 r1 = *(const float4*)&hbT[half*128 + q][4];
            const float hv[8] = {r0.x, r0.y, r0.z, r0.w, r1.x, r1.y, r1.z, r1.w};
            const float wq = w[q];
            acc[0] = fmaf(hv[0 ^ s], wq, acc[0]);
            acc[1] = fmaf(hv[1 ^ s], wq, acc[1]);
            acc[2] = fmaf(hv[2 ^ s], wq, acc[2]);
            acc[3] = fmaf(hv[3 ^ s], wq, acc[3]);
            acc[4] = fmaf(hv[4 ^ s], wq, acc[4]);
            acc[5] = fmaf(hv[5 ^ s], wq, acc[5]);
        }
        __syncthreads();

        // ---- partials (reuse hbT), same swizzle ----
        #pragma unroll
        for (int jj = 0; jj < JBATCH; ++jj)
            hbT[t][jj ^ sw] = acc[jj];
        __syncthreads();

        if (t < 128) {
            float v[JBATCH];
            #pragma unroll
            for (int jj = 0; jj < JBATCH; ++jj) {
                const float h2 = fmaxf(hbT[t][jj ^ sw] + hbT[t + 128][jj ^ sw] + b2c, 0.f);
                v[jj] = h2 * w3c;
            }
            #pragma unroll
            for (int jj = 0; jj < JBATCH; ++jj) {
                float s = v[jj];
                #pragma unroll
                for (int off = 32; off; off >>= 1) s += __shfl_down(s, off, 64);
                if ((t & 63) == 0) red[t >> 6][jj] = s;
            }
        }
        __syncthreads();
        if (t < JBATCH) {
            const int j = jb0 + t;
            const float s = red[0][t] + red[1][t] + b3v;
            out[i*NN + j] = (i == j) ? 0.f : 1.f / (1.f + __expf(-s));
        }
        __syncthreads();   // red/hbT safe before next batch
    }
}

// ---------------- Kernel C: conf [96,96,96] ----------------
// grid (96, 24): one i, 4 j per block. 192 threads = 2 groups of 96 (k lanes),
// each group owns 2 j accumulators. 2304 blocks = 9 blocks/CU exactly
// (27 waves/CU). sT[h][4] XOR-swizzled: conflict-free staging writes,
// one broadcast ds_read_b64 per h. Inner loop VALU-bound (6 VALU : 1 DS : 1 VMEM).
#define CJT 4
__global__ __launch_bounds__(192) void conf_kernel(
    const float* __restrict__ ta, const float* __restrict__ tb,
    const float* __restrict__ tcT, const float* __restrict__ V2,
    const float* __restrict__ c2, float* __restrict__ out)
{
    const int i  = blockIdx.x;
    const int j0 = blockIdx.y * CJT;    // 24 groups x 4 j
    const int t  = threadIdx.x;         // 0..191
    const int g  = (t >= NN) ? 1 : 0;
    const int k  = t - g*NN;            // 0..95

    __shared__ float sT[HH][CJT];       // 4 KB, XOR-swizzled columns

    for (int h = t; h < HH; h += 192) {
        const float tav = ta[i*HH + h];
        const int swx = (h >> 2) & 3;
        #pragma unroll
        for (int jj = 0; jj < CJT; ++jj)
            sT[h][jj ^ swx] = tav + tb[(j0 + jj)*HH + h];
    }
    __syncthreads();

    float acc0 = 0.f, acc1 = 0.f;
    for (int h0 = 0; h0 < HH; h0 += 32) {
        #pragma unroll
        for (int hh = 0; hh < 32; ++hh) {
            const int h  = h0 + hh;
            const int s  = (hh >> 2) & 3;            // == (h>>2)&3, compile-time
            const float tcx = tcT[h*NN + k];         // coalesced across k lanes
            const float v2x = V2[h];                 // uniform -> scalar load
            const float2 sv = *(const float2*)&sT[h][(g ^ (s >> 1)) * 2];
            const float s0 = (s & 1) ? sv.y : sv.x;  // value for m=0 (compile-time sel)
            const float s1 = (s & 1) ? sv.x : sv.y;  // value for m=1
            acc0 = fmaf(fmaxf(s0 + tcx, 0.f), v2x, acc0);
            acc1 = fmaf(fmaxf(s1 + tcx, 0.f), v2x, acc1);
        }
    }

    const float c2v = c2[0];
    {
        const int j = j0 + g*2 + 0;
        float val = 1.f / (1.f + __expf(-(acc0 + c2v)));
        if (i == j || i == k || j == k) val = 0.f;
        out[(i*NN + j)*NN + k] = val;
    }
    {
        const int j = j0 + g*2 + 1;
        float val = 1.f / (1.f + __expf(-(acc1 + c2v)));
        if (i == j || i == k || j == k) val = 0.f;
        out[(i*NN + j)*NN + k] = val;
    }
}

extern "C" void kernel_launch(void* const* d_in, const int* in_sizes, int n_in,
                              void* d_out, int out_size, void* d_ws, size_t ws_size,
                              hipStream_t stream) {
    const float* X  = (const float*)d_in[0];
    // d_in[1] = edge_index (unused by reference)
    const float* W1 = (const float*)d_in[2];
    const float* b1 = (const float*)d_in[3];
    const float* W2 = (const float*)d_in[4];
    const float* b2 = (const float*)d_in[5];
    const float* W3 = (const float*)d_in[6];
    const float* b3 = (const float*)d_in[7];
    const float* V1 = (const float*)d_in[8];
    const float* c1 = (const float*)d_in[9];
    const float* V2 = (const float*)d_in[10];
    const float* c2 = (const float*)d_in[11];

    float* out = (float*)d_out;
    float* ws  = (float*)d_ws;
    float* pi  = ws;                 // 96*256
    float* pj  = pi + NN*HH;
    float* ta  = pj + NN*HH;
    float* tb  = ta + NN*HH;
    float* tcT = tb + NN*HH;         // 256*96

    proj_kernel<<<NN, 256, 0, stream>>>(X, W1, b1, V1, c1, pi, pj, ta, tb, tcT);
    causal_kernel<<<dim3(NN, 8), 256, 0, stream>>>(pi, pj, W2, b2, W3, b3, out);
    conf_kernel<<<dim3(NN, 24), 192, 0, stream>>>(ta, tb, tcT, V2, c2, out + NN*NN);
}

// Round 2
// 48.840 us; speedup vs baseline: 2.2815x; 2.2815x over previous
//
#include <hip/hip_runtime.h>
#include <hip/hip_bf16.h>

#define NN 96
#define DD 64
#define HH 256
#define H2 128

// ---------------- Kernel A: projections ----------------
// pi = X@W1[:64] + b1, pj = X@W1[64:]
// ta = X@V1[:64] + c1, tb = X@V1[64:128], tcT[h][k] = (X@V1[128:])[k][h]
__global__ __launch_bounds__(256) void proj_kernel(
    const float* __restrict__ X, const float* __restrict__ W1, const float* __restrict__ b1,
    const float* __restrict__ V1, const float* __restrict__ c1,
    float* __restrict__ pi, float* __restrict__ pj,
    float* __restrict__ ta, float* __restrict__ tb, float* __restrict__ tcT)
{
    const int i = blockIdx.x;
    const int h = threadIdx.x;          // 0..255
    __shared__ float xs[DD];
    if (h < DD) xs[h] = X[i*DD + h];
    __syncthreads();
    float aPi = 0.f, aPj = 0.f, aTa = 0.f, aTb = 0.f, aTc = 0.f;
    #pragma unroll 8
    for (int d = 0; d < DD; ++d) {
        const float x = xs[d];
        aPi = fmaf(x, W1[d*HH + h],          aPi);
        aPj = fmaf(x, W1[(DD + d)*HH + h],   aPj);
        aTa = fmaf(x, V1[d*HH + h],          aTa);
        aTb = fmaf(x, V1[(DD + d)*HH + h],   aTb);
        aTc = fmaf(x, V1[(2*DD + d)*HH + h], aTc);
    }
    pi[i*HH + h] = aPi + b1[h];
    pj[i*HH + h] = aPj;
    ta[i*HH + h] = aTa + c1[h];
    tb[i*HH + h] = aTb;
    tcT[h*NN + i] = aTc;
}

// ---------------- Kernel B: causal [96,96] ----------------
// grid (96,8): 12 j per block (single batch). 256 threads:
//   c2 = t&63 (channel pair base: c2 and c2+64), qt = t>>6 (h-quarter).
// W2 streamed from L2 (2 coalesced loads/q serving 24 FMA) -> no 128-reg
// weight copy, low VGPR, high ILP. h-tile transposed hbT[256][12]; reads are
// wave-uniform b128 broadcasts (3 per q feeding 24 FMA).
__global__ __launch_bounds__(256) void causal_kernel(
    const float* __restrict__ pi, const float* __restrict__ pj,
    const float* __restrict__ W2, const float* __restrict__ b2,
    const float* __restrict__ W3, const float* __restrict__ b3,
    float* __restrict__ out)
{
    const int i  = blockIdx.x;
    const int j0 = blockIdx.y * 12;
    const int t  = threadIdx.x;         // 0..255
    const int c2 = t & 63;
    const int qt = t >> 6;              // 0..3

    __shared__ float smem[4*64*2*12];   // 24 KB; staging then partials
    __shared__ float red[2][12];
    float (*hb)[12]          = (float(*)[12])smem;          // [256][12]
    float (*part)[64][2][12] = (float(*)[64][2][12])smem;   // [4][64][2][12]

    // ---- stage hbT[h][jj] = relu(pi[i][h] + pj[j][h]), h = t ----
    {
        const float p_i = pi[i*HH + t];
        #pragma unroll
        for (int jj = 0; jj < 12; ++jj)
            hb[t][jj] = fmaxf(p_i + pj[(j0 + jj)*HH + t], 0.f);
    }
    __syncthreads();

    // ---- inner: acc{0,1}[jj] += h[q][jj] * W2[q][c2 / c2+64] over quarter ----
    float acc0[12], acc1[12];
    #pragma unroll
    for (int jj = 0; jj < 12; ++jj) { acc0[jj] = 0.f; acc1[jj] = 0.f; }

    const float* __restrict__ w2p = W2 + (qt*64)*H2 + c2;
    #pragma unroll 2
    for (int q = 0; q < 64; ++q) {
        const float wa = w2p[q*H2];
        const float wb = w2p[q*H2 + 64];
        const int hq = qt*64 + q;
        const float4 hA = *(const float4*)&hb[hq][0];
        const float4 hB = *(const float4*)&hb[hq][4];
        const float4 hC = *(const float4*)&hb[hq][8];
        const float hv[12] = {hA.x,hA.y,hA.z,hA.w, hB.x,hB.y,hB.z,hB.w, hC.x,hC.y,hC.z,hC.w};
        #pragma unroll
        for (int jj = 0; jj < 12; ++jj) {
            acc0[jj] = fmaf(hv[jj], wa, acc0[jj]);
            acc1[jj] = fmaf(hv[jj], wb, acc1[jj]);
        }
    }
    __syncthreads();          // all hb reads done before overwrite

    // ---- partials: part[qt][c2][cc][jj] ----
    #pragma unroll
    for (int b = 0; b < 3; ++b) {
        float4 p0, p1;
        p0.x = acc0[b*4+0]; p0.y = acc0[b*4+1]; p0.z = acc0[b*4+2]; p0.w = acc0[b*4+3];
        p1.x = acc1[b*4+0]; p1.y = acc1[b*4+1]; p1.z = acc1[b*4+2]; p1.w = acc1[b*4+3];
        *(float4*)&part[qt][c2][0][b*4] = p0;
        *(float4*)&part[qt][c2][1][b*4] = p1;
    }
    __syncthreads();

    // ---- reduce quarters, layer2 bias+relu, layer3 dot over 128 c ----
    if (t < 128) {
        const int c  = t;
        const int cl = t & 63;
        const int cc = t >> 6;
        const float b2c = b2[c];
        const float w3c = W3[c];
        float v[12];
        #pragma unroll
        for (int b = 0; b < 3; ++b) {
            float4 s; s.x = 0.f; s.y = 0.f; s.z = 0.f; s.w = 0.f;
            #pragma unroll
            for (int qq = 0; qq < 4; ++qq) {
                const float4 p = *(const float4*)&part[qq][cl][cc][b*4];
                s.x += p.x; s.y += p.y; s.z += p.z; s.w += p.w;
            }
            v[b*4+0] = fmaxf(s.x + b2c, 0.f) * w3c;
            v[b*4+1] = fmaxf(s.y + b2c, 0.f) * w3c;
            v[b*4+2] = fmaxf(s.z + b2c, 0.f) * w3c;
            v[b*4+3] = fmaxf(s.w + b2c, 0.f) * w3c;
        }
        #pragma unroll
        for (int jj = 0; jj < 12; ++jj) {
            float s = v[jj];
            #pragma unroll
            for (int off = 32; off; off >>= 1) s += __shfl_down(s, off, 64);
            if ((t & 63) == 0) red[t >> 6][jj] = s;
        }
    }
    __syncthreads();
    if (t < 12) {
        const int j = j0 + t;
        const float s = red[0][t] + red[1][t] + b3[0];
        out[i*NN + j] = (i == j) ? 0.f : 1.f / (1.f + __expf(-s));
    }
}

// ---------------- Kernel C: conf [96,96,96] ----------------
// grid (96,8) = 768 blocks = exactly 3/CU. 192 threads = 4 j-groups x 48
// k-lanes; each thread owns 3 j x 2 k accumulators (k = 2l, 2l+1 -> float2
// tc loads). Per 4-h chunk: 3 DS-b128 broadcast (s) : 4 VMEM-b64 (tc) :
// 72 FMA-triples -> VALU-bound with k-blocking halving LDS traffic.
#define CJT 12
#define CJG 3
__global__ __launch_bounds__(192) void conf_kernel(
    const float* __restrict__ ta, const float* __restrict__ tb,
    const float* __restrict__ tcT, const float* __restrict__ V2,
    const float* __restrict__ c2, float* __restrict__ out)
{
    const int i  = blockIdx.x;
    const int j0 = blockIdx.y * CJT;
    const int t  = threadIdx.x;         // 0..191
    const int g  = t / 48;              // j-group 0..3
    const int l  = t % 48;              // k-pair lane
    const int k0 = 2*l;                 // k = k0, k0+1

    __shared__ float sbuf[CJT][HH];     // 12 KB

    // ---- stage s[jj][h] = ta[i][h] + tb[j][h], vectorized ----
    for (int idx = t; idx < CJT*HH/4; idx += 192) {
        const int jj = idx >> 6;            // /64 float4s per row
        const int h4 = (idx & 63) << 2;
        const float4 a = *(const float4*)&ta[i*HH + h4];
        const float4 b = *(const float4*)&tb[(j0 + jj)*HH + h4];
        float4 s; s.x = a.x + b.x; s.y = a.y + b.y; s.z = a.z + b.z; s.w = a.w + b.w;
        *(float4*)&sbuf[jj][h4] = s;
    }
    __syncthreads();

    float acc[CJG][2];
    #pragma unroll
    for (int m = 0; m < CJG; ++m) { acc[m][0] = 0.f; acc[m][1] = 0.f; }

    const float* __restrict__ sb0 = &sbuf[g*CJG + 0][0];
    const float* __restrict__ sb1 = &sbuf[g*CJG + 1][0];
    const float* __restrict__ sb2 = &sbuf[g*CJG + 2][0];

    #pragma unroll 2
    for (int h0 = 0; h0 < HH; h0 += 4) {
        const float2 t0 = *(const float2*)&tcT[(h0+0)*NN + k0];
        const float2 t1 = *(const float2*)&tcT[(h0+1)*NN + k0];
        const float2 t2 = *(const float2*)&tcT[(h0+2)*NN + k0];
        const float2 t3 = *(const float2*)&tcT[(h0+3)*NN + k0];
        const float4 va = *(const float4*)&V2[h0];        // uniform -> scalar
        const float4 sA = *(const float4*)&sb0[h0];
        const float4 sB = *(const float4*)&sb1[h0];
        const float4 sC = *(const float4*)&sb2[h0];
        const float s[CJG][4] = {{sA.x,sA.y,sA.z,sA.w},
                                 {sB.x,sB.y,sB.z,sB.w},
                                 {sC.x,sC.y,sC.z,sC.w}};
        const float tc[4][2] = {{t0.x,t0.y},{t1.x,t1.y},{t2.x,t2.y},{t3.x,t3.y}};
        const float vv[4] = {va.x,va.y,va.z,va.w};
        #pragma unroll
        for (int u4 = 0; u4 < 4; ++u4) {
            #pragma unroll
            for (int m = 0; m < CJG; ++m) {
                acc[m][0] = fmaf(fmaxf(s[m][u4] + tc[u4][0], 0.f), vv[u4], acc[m][0]);
                acc[m][1] = fmaf(fmaxf(s[m][u4] + tc[u4][1], 0.f), vv[u4], acc[m][1]);
            }
        }
    }

    const float c2v = c2[0];
    #pragma unroll
    for (int m = 0; m < CJG; ++m) {
        const int j = j0 + g*CJG + m;
        float2 o;
        o.x = 1.f / (1.f + __expf(-(acc[m][0] + c2v)));
        o.y = 1.f / (1.f + __expf(-(acc[m][1] + c2v)));
        if (i == j || i == k0   || j == k0  ) o.x = 0.f;
        if (i == j || i == k0+1 || j == k0+1) o.y = 0.f;
        *(float2*)&out[(i*NN + j)*NN + k0] = o;
    }
}

extern "C" void kernel_launch(void* const* d_in, const int* in_sizes, int n_in,
                              void* d_out, int out_size, void* d_ws, size_t ws_size,
                              hipStream_t stream) {
    const float* X  = (const float*)d_in[0];
    // d_in[1] = edge_index (unused by reference)
    const float* W1 = (const float*)d_in[2];
    const float* b1 = (const float*)d_in[3];
    const float* W2 = (const float*)d_in[4];
    const float* b2 = (const float*)d_in[5];
    const float* W3 = (const float*)d_in[6];
    const float* b3 = (const float*)d_in[7];
    const float* V1 = (const float*)d_in[8];
    const float* c1 = (const float*)d_in[9];
    const float* V2 = (const float*)d_in[10];
    const float* c2 = (const float*)d_in[11];

    float* out = (float*)d_out;
    float* ws  = (float*)d_ws;
    float* pi  = ws;                 // 96*256
    float* pj  = pi + NN*HH;
    float* ta  = pj + NN*HH;
    float* tb  = ta + NN*HH;
    float* tcT = tb + NN*HH;         // 256*96

    proj_kernel<<<NN, 256, 0, stream>>>(X, W1, b1, V1, c1, pi, pj, ta, tb, tcT);
    causal_kernel<<<dim3(NN, 8), 256, 0, stream>>>(pi, pj, W2, b2, W3, b3, out);
    conf_kernel<<<dim3(NN, 8), 192, 0, stream>>>(ta, tb, tcT, V2, c2, out + NN*NN);
}